// Round 1
// baseline (389.136 us; speedup 1.0000x reference)
//
#include <hip/hip_runtime.h>

// Problem constants (match reference)
namespace {
constexpr int D    = 50;     // input_dim
constexpr int H    = 50;     // hidden_dim
constexpr int LDIM = 100;    // latent_dim
constexpr int C    = 10;     // 2*WIN context words
constexpr int B    = 65536;  // batch
constexpr int BLK  = 256;
constexpr int GRID = B / BLK;  // 256 blocks, exact

// KL(idx | mu, logsigma) = 0.5*( (exp(logs)+sum((mu-tm)^2)) * exp(-tlv) + tlv - logs - L )
__device__ __forceinline__ float kl_term(const float* __restrict__ mu,
                                         float ps, float logs, int idx,
                                         const float* __restrict__ tm_tbl,
                                         const float* __restrict__ tlv_tbl) {
  const float* tm = tm_tbl + (long)idx * LDIM;   // 400B-aligned rows -> float4 ok
  float tlv = tlv_tbl[idx];
  float d0 = 0.f, d1 = 0.f, d2 = 0.f, d3 = 0.f;
#pragma unroll
  for (int l = 0; l < LDIM; l += 4) {
    float4 t = *reinterpret_cast<const float4*>(tm + l);
    float a0 = mu[l + 0] - t.x;
    float a1 = mu[l + 1] - t.y;
    float a2 = mu[l + 2] - t.z;
    float a3 = mu[l + 3] - t.w;
    d0 = fmaf(a0, a0, d0);
    d1 = fmaf(a1, a1, d1);
    d2 = fmaf(a2, a2, d2);
    d3 = fmaf(a3, a3, d3);
  }
  float dsum = (d0 + d1) + (d2 + d3);
  float itv  = __expf(-tlv);
  return 0.5f * (fmaf(ps + dsum, itv, tlv - logs) - (float)LDIM);
}

__global__ __launch_bounds__(BLK) void bsg_fwd_kernel(
    const float* __restrict__ emb,       // [V,D]
    const float* __restrict__ W1,        // [2D,H]
    const float* __restrict__ b1,        // [H]
    const float* __restrict__ Wmu,       // [H,L]
    const float* __restrict__ bmu,       // [L]
    const float* __restrict__ Wls,       // [H]
    const float* __restrict__ bls,       // [1]
    const float* __restrict__ tm_tbl,    // [V,L]
    const float* __restrict__ tlv_tbl,   // [V]
    const int*   __restrict__ centers,   // [B]
    const int*   __restrict__ contexts,  // [B,C]
    const int*   __restrict__ negctx,    // [B,C]
    float* __restrict__ partials)        // [GRID]
{
  const int b = blockIdx.x * BLK + threadIdx.x;  // exact: GRID*BLK == B

  const int cen = centers[b];

  // ---- load center embedding (rows are 8B aligned: idx*200B) ----
  float ecen[D];
  {
    const float* ep = emb + (long)cen * D;
#pragma unroll
    for (int f = 0; f < D; f += 2) {
      float2 v = *reinterpret_cast<const float2*>(ep + f);
      ecen[f] = v.x; ecen[f + 1] = v.y;
    }
  }

  // ---- z[j] = b1[j] + sum_f ecen[f] * W1[(D+f)*H + j]  (shared across contexts) ----
  float z[H];
#pragma unroll
  for (int j = 0; j < H; ++j) z[j] = b1[j];
#pragma unroll
  for (int f = 0; f < D; ++f) {
    const float vf = ecen[f];
#pragma unroll
    for (int j = 0; j < H; ++j) z[j] = fmaf(vf, W1[(D + f) * H + j], z[j]);
  }

  // ---- h[j] = sum_c relu( z[j] + sum_f ectx[f]*W1[f*H+j] ) ----
  float h[H];
#pragma unroll
  for (int j = 0; j < H; ++j) h[j] = 0.f;

  for (int c = 0; c < C; ++c) {  // runtime loop (keeps code size sane)
    const int idx = contexts[b * C + c];
    const float* ecp = emb + (long)idx * D;
    float ectx[D];
#pragma unroll
    for (int f = 0; f < D; f += 2) {
      float2 v = *reinterpret_cast<const float2*>(ecp + f);
      ectx[f] = v.x; ectx[f + 1] = v.y;
    }
    float s[H];
#pragma unroll
    for (int j = 0; j < H; ++j) s[j] = z[j];
#pragma unroll
    for (int f = 0; f < D; ++f) {
      const float vf = ectx[f];
#pragma unroll
      for (int j = 0; j < H; ++j) s[j] = fmaf(vf, W1[f * H + j], s[j]);
    }
#pragma unroll
    for (int j = 0; j < H; ++j) h[j] += fmaxf(s[j], 0.f);
  }

  // ---- mu = h @ Wmu + bmu ; logs = h @ Wls + bls ----
  float mu[LDIM];
#pragma unroll
  for (int l = 0; l < LDIM; ++l) mu[l] = bmu[l];
#pragma unroll
  for (int j = 0; j < H; ++j) {
    const float hj = h[j];
#pragma unroll
    for (int l = 0; l < LDIM; ++l) mu[l] = fmaf(hj, Wmu[j * LDIM + l], mu[l]);
  }
  float logs = bls[0];
#pragma unroll
  for (int j = 0; j < H; ++j) logs = fmaf(h[j], Wls[j], logs);
  const float ps = __expf(logs);

  // ---- KL terms + hinge ----
  float acc = kl_term(mu, ps, logs, cen, tm_tbl, tlv_tbl);
  for (int c = 0; c < C; ++c) {
    const int ic = contexts[b * C + c];
    const int in = negctx[b * C + c];
    const float kc = kl_term(mu, ps, logs, ic, tm_tbl, tlv_tbl);
    const float kn = kl_term(mu, ps, logs, in, tm_tbl, tlv_tbl);
    acc += fmaxf(kc - kn + 1.0f, 0.f);
  }

  // ---- block reduction (deterministic) ----
  float vsum = acc;
#pragma unroll
  for (int off = 32; off > 0; off >>= 1) vsum += __shfl_down(vsum, off);
  __shared__ float wsum[BLK / 64];
  if ((threadIdx.x & 63) == 0) wsum[threadIdx.x >> 6] = vsum;
  __syncthreads();
  if (threadIdx.x == 0) {
    float t = 0.f;
#pragma unroll
    for (int w = 0; w < BLK / 64; ++w) t += wsum[w];
    partials[blockIdx.x] = t;
  }
}

__global__ __launch_bounds__(GRID) void bsg_reduce_kernel(const float* __restrict__ partials,
                                                          float* __restrict__ out) {
  // GRID == 256 threads, one block; deterministic tree reduction in double.
  double v = (double)partials[threadIdx.x];
#pragma unroll
  for (int off = 32; off > 0; off >>= 1) v += __shfl_down(v, off);
  __shared__ double ws[GRID / 64];
  if ((threadIdx.x & 63) == 0) ws[threadIdx.x >> 6] = v;
  __syncthreads();
  if (threadIdx.x == 0) {
    double t = 0.0;
#pragma unroll
    for (int w = 0; w < GRID / 64; ++w) t += ws[w];
    out[0] = (float)(t / (double)B);
  }
}
}  // namespace

extern "C" void kernel_launch(void* const* d_in, const int* in_sizes, int n_in,
                              void* d_out, int out_size, void* d_ws, size_t ws_size,
                              hipStream_t stream) {
  const float* emb     = (const float*)d_in[0];
  const float* W1      = (const float*)d_in[1];
  const float* b1      = (const float*)d_in[2];
  const float* Wmu     = (const float*)d_in[3];
  const float* bmu     = (const float*)d_in[4];
  const float* Wls     = (const float*)d_in[5];
  const float* bls     = (const float*)d_in[6];
  const float* tm_tbl  = (const float*)d_in[7];
  const float* tlv_tbl = (const float*)d_in[8];
  const int*   centers = (const int*)d_in[9];
  const int*   ctx     = (const int*)d_in[10];
  const int*   negc    = (const int*)d_in[11];

  float* partials = (float*)d_ws;  // GRID floats
  float* out      = (float*)d_out;

  bsg_fwd_kernel<<<GRID, BLK, 0, stream>>>(emb, W1, b1, Wmu, bmu, Wls, bls,
                                           tm_tbl, tlv_tbl, centers, ctx, negc,
                                           partials);
  bsg_reduce_kernel<<<1, GRID, 0, stream>>>(partials, out);
}